// Round 16
// baseline (272.822 us; speedup 1.0000x reference)
//
#include <hip/hip_runtime.h>
#include <math.h>

#define N_NODES 50000
#define N_EDGES 800000
#define IN_DIM  9
#define HIDDEN  256
#define N_CAND  4096

#define SCAN_TPB 256
#define SCAN_NB  ((N_NODES + SCAN_TPB - 1) / SCAN_TPB)   // 196

// ---------------- CSR build ----------------

// 4 edges per thread, int4 coalesced index reads.
__global__ void hist_kernel(const int* __restrict__ dst, int* __restrict__ cnt) {
    int base = (blockIdx.x * blockDim.x + threadIdx.x) * 4;
    if (base >= N_EDGES) return;   // N_EDGES % 4 == 0
    int4 d4 = *(const int4*)(dst + base);
    atomicAdd(&cnt[d4.x], 1);
    atomicAdd(&cnt[d4.y], 1);
    atomicAdd(&cnt[d4.z], 1);
    atomicAdd(&cnt[d4.w], 1);
}

__global__ __launch_bounds__(SCAN_TPB) void scan1_kernel(const int* __restrict__ cnt,
                                                         int* __restrict__ row_ptr,
                                                         int* __restrict__ blockSums) {
    __shared__ int s[SCAN_TPB];
    int t = threadIdx.x;
    int i = blockIdx.x * SCAN_TPB + t;
    int v = (i < N_NODES) ? cnt[i] : 0;
    s[t] = v;
    __syncthreads();
#pragma unroll
    for (int off = 1; off < SCAN_TPB; off <<= 1) {
        int u = (t >= off) ? s[t - off] : 0;
        __syncthreads();
        s[t] += u;
        __syncthreads();
    }
    if (i < N_NODES) row_ptr[i] = s[t] - v;          // exclusive within block
    if (t == SCAN_TPB - 1) blockSums[blockIdx.x] = s[t];  // block total
}

__global__ __launch_bounds__(SCAN_TPB) void scan2_kernel(const int* __restrict__ blockSums,
                                                         int* __restrict__ blockOff,
                                                         int* __restrict__ row_ptr) {
    __shared__ int s[SCAN_TPB];
    int t = threadIdx.x;
    int v = (t < SCAN_NB) ? blockSums[t] : 0;
    s[t] = v;
    __syncthreads();
#pragma unroll
    for (int off = 1; off < SCAN_TPB; off <<= 1) {
        int u = (t >= off) ? s[t - off] : 0;
        __syncthreads();
        s[t] += u;
        __syncthreads();
    }
    if (t < SCAN_NB) blockOff[t] = s[t] - v;
    if (t == SCAN_TPB - 1) row_ptr[N_NODES] = s[t];
}

// Phase 3: finalize row_ptr, init cur = row_ptr (fill's atomicAdd return IS the
// final slot -> no scattered row_ptr[d] read per edge), compute dinv.
__global__ __launch_bounds__(SCAN_TPB) void scan3_kernel(const int* __restrict__ cnt,
                                                         const int* __restrict__ blockOff,
                                                         int* __restrict__ row_ptr,
                                                         int* __restrict__ cur,
                                                         float* __restrict__ dinv) {
    int i = blockIdx.x * SCAN_TPB + threadIdx.x;
    if (i < N_NODES) {
        int rp = row_ptr[i] + blockOff[blockIdx.x];
        row_ptr[i] = rp;
        cur[i] = rp;
        dinv[i] = 1.0f / sqrtf((float)(cnt[i] + 1));
    }
}

// 4 edges per thread: int4 coalesced index reads, 4 independent atomic chains.
__global__ void fill_kernel(const int* __restrict__ srcv, const int* __restrict__ dstv,
                            int* __restrict__ cur, int* __restrict__ col) {
    int base = (blockIdx.x * blockDim.x + threadIdx.x) * 4;
    if (base >= N_EDGES) return;   // N_EDGES % 4 == 0
    int4 d4 = *(const int4*)(dstv + base);
    int4 s4 = *(const int4*)(srcv + base);
    int p0 = atomicAdd(&cur[d4.x], 1);
    int p1 = atomicAdd(&cur[d4.y], 1);
    int p2 = atomicAdd(&cur[d4.z], 1);
    int p3 = atomicAdd(&cur[d4.w], 1);
    col[p0] = s4.x;
    col[p1] = s4.y;
    col[p2] = s4.z;
    col[p3] = s4.w;
}

// ---------------- Layer-1 aggregation on RAW 9-dim features ----------------
// 16 lanes per node; 4-step shfl_xor reduce within aligned 16-lane groups.

__global__ __launch_bounds__(256) void aggx_kernel(const float* __restrict__ x,
                                                   const int* __restrict__ row_ptr,
                                                   const int* __restrict__ col,
                                                   const float* __restrict__ dinv,
                                                   float* __restrict__ ax) {
    int tid  = threadIdx.x;
    int node = blockIdx.x * 16 + (tid >> 4);
    int l    = tid & 15;
    if (node >= N_NODES) return;

    float a[IN_DIM];
#pragma unroll
    for (int d = 0; d < IN_DIM; ++d) a[d] = 0.f;

    int beg = row_ptr[node], end = row_ptr[node + 1];
    for (int j = beg + l; j < end; j += 16) {
        int s = col[j];
        float w = dinv[s];
        const float* xs = x + (size_t)s * IN_DIM;
#pragma unroll
        for (int d = 0; d < IN_DIM; ++d) a[d] += w * xs[d];
    }

#pragma unroll
    for (int m = 8; m >= 1; m >>= 1) {
#pragma unroll
        for (int d = 0; d < IN_DIM; ++d) a[d] += __shfl_xor(a[d], m);
    }

    float di = dinv[node];
    const float* xi = x + (size_t)node * IN_DIM;
    float o[IN_DIM];
#pragma unroll
    for (int d = 0; d < IN_DIM; ++d) o[d] = di * (di * xi[d] + a[d]);

    float v = o[0];
    if (l == 1) v = o[1];
    if (l == 2) v = o[2];
    if (l == 3) v = o[3];
    if (l == 4) v = o[4];
    if (l == 5) v = o[5];
    if (l == 6) v = o[6];
    if (l == 7) v = o[7];
    if (l == 8) v = o[8];
    if (l < IN_DIM) ax[(size_t)node * IN_DIM + l] = v;
}

// ---------------- h1 = relu(ax @ W1 + b1), all nodes ----------------

#define NPB 8
__global__ __launch_bounds__(256) void h1_kernel(const float* __restrict__ ax,
                                                 const float* __restrict__ W1,
                                                 const float* __restrict__ b1,
                                                 float* __restrict__ h1) {
    int n0 = blockIdx.x * NPB;
    int c = threadIdx.x;
    __shared__ float s[NPB][IN_DIM];
    if (c < NPB * IN_DIM) s[c / IN_DIM][c % IN_DIM] = ax[(size_t)n0 * IN_DIM + c];
    __syncthreads();
    float w[IN_DIM];
#pragma unroll
    for (int k = 0; k < IN_DIM; ++k) w[k] = W1[k * HIDDEN + c];
    float b = b1[c];
#pragma unroll
    for (int r = 0; r < NPB; ++r) {
        float acc = b;
#pragma unroll
        for (int k = 0; k < IN_DIM; ++k) acc += s[r][k] * w[k];
        h1[(size_t)(n0 + r) * HIDDEN + c] = fmaxf(acc, 0.f);
    }
}

// ---------------- Candidate-only aggregation of h1 ----------------

__global__ __launch_bounds__(256) void aggc_kernel(const float* __restrict__ h1,
                                                   const int* __restrict__ cand,
                                                   const int* __restrict__ row_ptr,
                                                   const int* __restrict__ col,
                                                   const float* __restrict__ dinv,
                                                   float* __restrict__ g) {
    int k = blockIdx.x * 4 + (threadIdx.x >> 6);
    if (k >= N_CAND) return;
    int lane = threadIdx.x & 63;
    int node = cand[k];
    const float di = dinv[node];
    float4 v = ((const float4*)(h1 + (size_t)node * HIDDEN))[lane];
    float4 acc = make_float4(di * v.x, di * v.y, di * v.z, di * v.w);
    int j = row_ptr[node], end = row_ptr[node + 1];
    for (; j < end; ++j) {
        int s = col[j];
        float w = dinv[s];
        float4 mv = ((const float4*)(h1 + (size_t)s * HIDDEN))[lane];
        acc.x += w * mv.x; acc.y += w * mv.y; acc.z += w * mv.z; acc.w += w * mv.w;
    }
    float4 o = make_float4(di * acc.x, di * acc.y, di * acc.z, di * acc.w);
    ((float4*)(g + (size_t)k * HIDDEN))[lane] = o;
}

// ---------------- Fused candidate head: register-blocked GEMM ----------------
// TM=16 cands/block, 256 threads; thread = 4 cands x 4 cols (acc[4][4], 16
// indep FMA chains). Wave w owns cands 4w..4w+3; lane l owns cols 4l..4l+3.
// Per k: ONE coalesced float4 weight load (1KB/wave, L1-shared across waves) +
// 4 wave-uniform LDS broadcasts + 16 FMAs -> 16 FMA/weight-float4 (was 4
// FMA/weight-float at CPB=4). Measured CPB curve 16->70us, 4->44, 2->51 showed
// reuse-per-load, not TLP, is the binding constraint. 1 wave/SIMD occupancy is
// covered by ILP=16. No unroll pragma / min-waves (R9 spill lesson); weight
// indexing stays lane-coalesced W[k*256+c] (R13 divergence lesson).

#define TM 16
__global__ __launch_bounds__(256) void head_fused_kernel(const float* __restrict__ g,
                                                         const float* __restrict__ W2,
                                                         const float* __restrict__ b2,
                                                         const float* __restrict__ Wh1,
                                                         const float* __restrict__ bh1,
                                                         const float* __restrict__ Wh2,
                                                         const float* __restrict__ bh2,
                                                         float* __restrict__ out) {
    __shared__ float A[TM][HIDDEN];   // 16 KB: g tile, then h2 tile
    int tid = threadIdx.x;
    int k0 = blockIdx.x * TM;
    int rw = (tid >> 6) * 4;          // wave's first candidate row
    int c0 = (tid & 63) * 4;          // thread's 4 columns

    // load A tile: 16 consecutive g rows = 4096 contiguous floats
    {
        const float4* gp = (const float4*)(g + (size_t)k0 * HIDDEN);
        float4* Ap = (float4*)&A[0][0];
#pragma unroll
        for (int it = 0; it < (TM * HIDDEN / 4) / 256; ++it)
            Ap[tid + it * 256] = gp[tid + it * 256];
    }
    __syncthreads();

    float acc[4][4];

    // stage 1: h2 = relu(A @ W2 + b2)
    {
        float4 bb = *(const float4*)(b2 + c0);
#pragma unroll
        for (int i = 0; i < 4; ++i) {
            acc[i][0] = bb.x; acc[i][1] = bb.y; acc[i][2] = bb.z; acc[i][3] = bb.w;
        }
        for (int k = 0; k < HIDDEN; ++k) {
            float4 w = *(const float4*)(W2 + (size_t)k * HIDDEN + c0);
            float a0 = A[rw + 0][k], a1 = A[rw + 1][k];
            float a2 = A[rw + 2][k], a3 = A[rw + 3][k];
            acc[0][0] += a0 * w.x; acc[0][1] += a0 * w.y; acc[0][2] += a0 * w.z; acc[0][3] += a0 * w.w;
            acc[1][0] += a1 * w.x; acc[1][1] += a1 * w.y; acc[1][2] += a1 * w.z; acc[1][3] += a1 * w.w;
            acc[2][0] += a2 * w.x; acc[2][1] += a2 * w.y; acc[2][2] += a2 * w.z; acc[2][3] += a2 * w.w;
            acc[3][0] += a3 * w.x; acc[3][1] += a3 * w.y; acc[3][2] += a3 * w.z; acc[3][3] += a3 * w.w;
        }
    }
    __syncthreads();   // all waves done reading g-tile
#pragma unroll
    for (int i = 0; i < 4; ++i) {
        float4 v;
        v.x = fmaxf(acc[i][0], 0.f); v.y = fmaxf(acc[i][1], 0.f);
        v.z = fmaxf(acc[i][2], 0.f); v.w = fmaxf(acc[i][3], 0.f);
        *(float4*)&A[rw + i][c0] = v;
    }
    __syncthreads();   // h2 tile complete

    // stage 2: t = tanh(A @ Wh1 + bh1) * Wh2
    {
        float4 bb = *(const float4*)(bh1 + c0);
#pragma unroll
        for (int i = 0; i < 4; ++i) {
            acc[i][0] = bb.x; acc[i][1] = bb.y; acc[i][2] = bb.z; acc[i][3] = bb.w;
        }
        for (int k = 0; k < HIDDEN; ++k) {
            float4 w = *(const float4*)(Wh1 + (size_t)k * HIDDEN + c0);
            float a0 = A[rw + 0][k], a1 = A[rw + 1][k];
            float a2 = A[rw + 2][k], a3 = A[rw + 3][k];
            acc[0][0] += a0 * w.x; acc[0][1] += a0 * w.y; acc[0][2] += a0 * w.z; acc[0][3] += a0 * w.w;
            acc[1][0] += a1 * w.x; acc[1][1] += a1 * w.y; acc[1][2] += a1 * w.z; acc[1][3] += a1 * w.w;
            acc[2][0] += a2 * w.x; acc[2][1] += a2 * w.y; acc[2][2] += a2 * w.z; acc[2][3] += a2 * w.w;
            acc[3][0] += a3 * w.x; acc[3][1] += a3 * w.y; acc[3][2] += a3 * w.z; acc[3][3] += a3 * w.w;
        }
    }
    float4 w2v = *(const float4*)(Wh2 + c0);
    float s[4];
#pragma unroll
    for (int i = 0; i < 4; ++i)
        s[i] = tanhf(acc[i][0]) * w2v.x + tanhf(acc[i][1]) * w2v.y +
               tanhf(acc[i][2]) * w2v.z + tanhf(acc[i][3]) * w2v.w;

    // per-wave reduction: 64 lanes cover all 256 cols for the wave's 4 cands
#pragma unroll
    for (int off = 32; off > 0; off >>= 1) {
#pragma unroll
        for (int i = 0; i < 4; ++i) s[i] += __shfl_down(s[i], off);
    }
    if ((tid & 63) == 0) {
        float b = bh2[0];
#pragma unroll
        for (int i = 0; i < 4; ++i) out[k0 + rw + i] = s[i] + b;
    }
}

// ---------------- launch ----------------

extern "C" void kernel_launch(void* const* d_in, const int* in_sizes, int n_in,
                              void* d_out, int out_size, void* d_ws, size_t ws_size,
                              hipStream_t stream) {
    const float* x   = (const float*)d_in[0];
    const float* W1  = (const float*)d_in[1];
    const float* b1  = (const float*)d_in[2];
    const float* W2  = (const float*)d_in[3];
    const float* b2  = (const float*)d_in[4];
    const float* Wh1 = (const float*)d_in[5];
    const float* bh1 = (const float*)d_in[6];
    const float* Wh2 = (const float*)d_in[7];
    const float* bh2 = (const float*)d_in[8];
    const int* edge_index = (const int*)d_in[9];   // [2, E]: src then dst
    const int* cand       = (const int*)d_in[10];
    float* out = (float*)d_out;

    char* ws = (char*)d_ws;
    size_t off = 0;
    auto alloc = [&](size_t bytes) -> void* {
        void* p = ws + off;
        off += (bytes + 255) & ~(size_t)255;
        return p;
    };
    int*   cnt       = (int*)alloc((size_t)N_NODES * 4);
    int*   row_ptr   = (int*)alloc((size_t)(N_NODES + 1) * 4);
    int*   cur       = (int*)alloc((size_t)N_NODES * 4);
    float* dinv      = (float*)alloc((size_t)N_NODES * 4);
    int*   blockSums = (int*)alloc((size_t)SCAN_NB * 4);
    int*   blockOff  = (int*)alloc((size_t)SCAN_NB * 4);
    int*   col       = (int*)alloc((size_t)N_EDGES * 4);
    float* ax        = (float*)alloc((size_t)N_NODES * IN_DIM * 4);
    float* h1        = (float*)alloc((size_t)N_NODES * HIDDEN * 4);
    float* g         = (float*)alloc((size_t)N_CAND * HIDDEN * 4);

    const int* src = edge_index;
    const int* dst = edge_index + N_EDGES;

    hipMemsetAsync(cnt, 0, (size_t)N_NODES * 4, stream);

    const int E4B = (N_EDGES / 4 + 255) / 256;
    hist_kernel<<<E4B, 256, 0, stream>>>(dst, cnt);
    scan1_kernel<<<SCAN_NB, SCAN_TPB, 0, stream>>>(cnt, row_ptr, blockSums);
    scan2_kernel<<<1, SCAN_TPB, 0, stream>>>(blockSums, blockOff, row_ptr);
    scan3_kernel<<<SCAN_NB, SCAN_TPB, 0, stream>>>(cnt, blockOff, row_ptr, cur, dinv);
    fill_kernel<<<E4B, 256, 0, stream>>>(src, dst, cur, col);

    aggx_kernel<<<(N_NODES + 15) / 16, 256, 0, stream>>>(x, row_ptr, col, dinv, ax);
    h1_kernel<<<N_NODES / NPB, 256, 0, stream>>>(ax, W1, b1, h1);
    aggc_kernel<<<(N_CAND + 3) / 4, 256, 0, stream>>>(h1, cand, row_ptr, col, dinv, g);
    head_fused_kernel<<<N_CAND / TM, 256, 0, stream>>>(g, W2, b2, Wh1, bh1, Wh2, bh2, out);
}